// Round 2
// baseline (695.454 us; speedup 1.0000x reference)
//
#include <hip/hip_runtime.h>

// Segment sum, chunked-atomic design (no offsets pass, no workspace).
// feat [N_NODES,128] f32, sorted segment_ids [N_NODES] i32 -> out [4096,128] f32.
//
// Kernel 1: zero out (2 MB, ~2 us).
// Kernel 2: grid of fixed 256-row chunks (perfect load balance, single round-ish
// residency, no dependency on a boundary pass). Each block streams its
// contiguous 128 KB chunk with the R0-proven pattern: nt float4 loads, 4-deep
// ILP, 32 rows/block-iter, lane = (c4 column slot, roff row phase).
// Per-lane running (cur_id, acc); ids sorted => flush only on id change
// (~2 flushes/lane) via unsafeAtomicAdd (HW global_atomic_add_f32).
// Low contention: <=16 lanes ever touch one output dword from <=2 blocks.

#define D_FEAT 128
#define D4     32   // float4 per row
#define CHUNK  256  // rows per block

typedef float f32x4 __attribute__((ext_vector_type(4)));

__global__ __launch_bounds__(256) void zero_out_kernel(
        float* __restrict__ out, int n_f4) {
    int i = blockIdx.x * blockDim.x + threadIdx.x;
    if (i < n_f4) {
        f32x4 z = {0.f, 0.f, 0.f, 0.f};
        ((f32x4*)out)[i] = z;
    }
}

__global__ __launch_bounds__(256) void SumNode_11905649344609_kernel(
        const float* __restrict__ feat,
        const int* __restrict__ ids,
        float* __restrict__ out,
        int n_nodes) {
    const int tid  = threadIdx.x;
    const int c4   = tid & (D4 - 1);   // float4 column slot 0..31
    const int roff = tid >> 5;         // row phase 0..7

    const int base = blockIdx.x * CHUNK;
    const int end  = (base + CHUNK < n_nodes) ? (base + CHUNK) : n_nodes;

    const f32x4* __restrict__ f4 = (const f32x4*)feat;

    f32x4 acc = {0.f, 0.f, 0.f, 0.f};
    int   cur = -1;                    // current segment id for this lane

    auto flush = [&]() {
        if (cur >= 0) {
            float* p = out + (size_t)cur * D_FEAT + c4 * 4;
            unsafeAtomicAdd(p + 0, acc[0]);
            unsafeAtomicAdd(p + 1, acc[1]);
            unsafeAtomicAdd(p + 2, acc[2]);
            unsafeAtomicAdd(p + 3, acc[3]);
        }
    };
    auto proc = [&](int id, f32x4 v) {
        if (__builtin_expect(id != cur, 0)) {
            flush();
            acc = (f32x4){0.f, 0.f, 0.f, 0.f};
            cur = id;
        }
        acc += v;
    };

    int r = base + roff;
    // Main loop: 32 rows per block-iteration, 4 independent loads per lane.
    for (; r + 24 < end; r += 32) {
        f32x4 v0 = __builtin_nontemporal_load(&f4[(size_t)(r)      * D4 + c4]);
        f32x4 v1 = __builtin_nontemporal_load(&f4[(size_t)(r +  8) * D4 + c4]);
        f32x4 v2 = __builtin_nontemporal_load(&f4[(size_t)(r + 16) * D4 + c4]);
        f32x4 v3 = __builtin_nontemporal_load(&f4[(size_t)(r + 24) * D4 + c4]);
        int i0 = ids[r];
        int i1 = ids[r + 8];
        int i2 = ids[r + 16];
        int i3 = ids[r + 24];
        proc(i0, v0);
        proc(i1, v1);
        proc(i2, v2);
        proc(i3, v3);
    }
    // Tail: 8 rows at a time, per-lane bound check.
    for (; r < end; r += 8) {
        f32x4 v = __builtin_nontemporal_load(&f4[(size_t)r * D4 + c4]);
        proc(ids[r], v);
    }
    flush();
}

extern "C" void kernel_launch(void* const* d_in, const int* in_sizes, int n_in,
                              void* d_out, int out_size, void* d_ws, size_t ws_size,
                              hipStream_t stream) {
    const float* feat = (const float*)d_in[0];
    const int*   ids  = (const int*)d_in[1];
    float*       out  = (float*)d_out;

    const int n_nodes = in_sizes[1];           // 1,000,000
    const int n_f4    = out_size / 4;          // out_size in floats -> f32x4 count

    zero_out_kernel<<<(n_f4 + 255) / 256, 256, 0, stream>>>(out, n_f4);

    const int n_chunks = (n_nodes + CHUNK - 1) / CHUNK;   // 3907
    SumNode_11905649344609_kernel<<<n_chunks, 256, 0, stream>>>(
        feat, ids, out, n_nodes);
}